// Round 8
// baseline (453.916 us; speedup 1.0000x reference)
//
#include <hip/hip_runtime.h>
#include <cstdint>
#include <cstddef>

constexpr int kC = 1024;   // DIM
constexpr int kH = 16;     // heads
constexpr int kB = 4;      // batch
constexpr int kN = 2048;   // seq
constexpr int kD = 64;     // head dim

typedef unsigned short u16;
typedef unsigned int   u32;
typedef unsigned long long u64;
typedef __bf16 v8bf  __attribute__((ext_vector_type(8)));
typedef float  v4f   __attribute__((ext_vector_type(4)));
typedef u16    u16x8 __attribute__((ext_vector_type(8)));
typedef u16    u16x4 __attribute__((ext_vector_type(4)));
typedef u16    u16x2 __attribute__((ext_vector_type(2)));

// packed fp32x2 -> bf16x2 (1 instr on gfx950; manual RNE fallback)
__device__ inline u32 f2bf_pk(float a, float b) {
#if __has_builtin(__builtin_amdgcn_cvt_pk_bf16_f32)
    return __builtin_bit_cast(u32, __builtin_amdgcn_cvt_pk_bf16_f32(a, b));
#else
    union { float f; u32 u; } x, y; x.f = a; y.f = b;
    const u32 ra = (x.u + 0x7FFFu + ((x.u >> 16) & 1u)) >> 16;
    const u32 rb = (y.u + 0x7FFFu + ((y.u >> 16) & 1u)) >> 16;
    return ra | (rb << 16);
#endif
}
__device__ inline u16 f2bf(float f) { return (u16)(f2bf_pk(f, f) & 0xffffu); }

__device__ inline float fexp2(float x) {
#if __has_builtin(__builtin_amdgcn_exp2f)
    return __builtin_amdgcn_exp2f(x);
#else
    return exp2f(x);
#endif
}
constexpr float kScaleLog2e = 0.18033688011112042f;  // 0.125 * log2(e)

// async 16B global -> LDS (wave-uniform LDS base + lane*16)
__device__ inline void gl2lds16(const u16* g, u16* l) {
    __builtin_amdgcn_global_load_lds(
        (const __attribute__((address_space(1))) void*)g,
        (__attribute__((address_space(3))) void*)l, 16, 0, 0);
}

// ---------------------------------------------------------------- casts
__global__ __launch_bounds__(256) void cast_bf16_kernel(
    const float* __restrict__ in, u16* __restrict__ outp)
{
    const int i = blockIdx.x * 256 + threadIdx.x;
    const float4 f = ((const float4*)in)[i];
    uint2 o; o.x = f2bf_pk(f.x, f.y); o.y = f2bf_pk(f.z, f.w);
    ((uint2*)outp)[i] = o;
}

// W [R][Cc] fp32 -> Wt [Cc][R] bf16, 64x64 LDS tiles
__global__ __launch_bounds__(256) void tpose_cast_kernel(
    const float* __restrict__ W, u16* __restrict__ Wt, int R, int Cc)
{
    __shared__ u16 tile[64][65];
    const int c0 = blockIdx.x * 64;
    const int r0 = blockIdx.y * 64;
    const int t  = threadIdx.x;
#pragma unroll
    for (int it = 0; it < 16; ++it) {
        const int r = it * 4 + (t >> 6);
        const int c = t & 63;
        tile[c][r] = f2bf(W[(size_t)(r0 + r) * Cc + c0 + c]);
    }
    __syncthreads();
#pragma unroll
    for (int it = 0; it < 16; ++it) {
        const int rr = it * 4 + (t >> 6);
        const int cc = t & 63;
        Wt[(size_t)(c0 + rr) * R + r0 + cc] = tile[rr][cc];
    }
}

// ------------------------------------------------------------ mask pack
// mask int32 [B,N,N] -> bits: row (b*N+q) = 2048 bits, bit k set iff masked.
__global__ __launch_bounds__(256) void maskpack_kernel(
    const int* __restrict__ mask, u32* __restrict__ bits)
{
    const int seg  = blockIdx.x * 4 + (threadIdx.x >> 6);
    const int lane = threadIdx.x & 63;
    const size_t row = (size_t)(seg >> 5);
    const int s = seg & 31;
    const int m = mask[row * kN + s * 64 + lane];
    const u64 bal = __ballot(m != 0);
    if (lane == 0) ((u64*)bits)[row * 32 + s] = bal;
}

// ---------------------------------------------------- bf16 MFMA GEMM
// C[M,N] = A[M,K] @ Bt[N,K]^T + bias.  128x128 tile, BK=32, 4 waves.
template <int MODE>
__global__ __launch_bounds__(256) void gemm_mfma_kernel(
    const u16* __restrict__ A, const u16* __restrict__ Bt,
    const float* __restrict__ bias, float* __restrict__ Cout,
    u16* __restrict__ qOut, u16* __restrict__ kOut, u16* __restrict__ vOut,
    int M, int N, int K)
{
    __shared__ u16 As[128 * 32];
    __shared__ u16 Bs[128 * 32];
    const int t    = threadIdx.x;
    const int w    = t >> 6;
    const int lane = t & 63;
    const int quad = lane >> 4;
    const int l16  = lane & 15;
    const int m0   = blockIdx.y * 128;
    const int n0   = blockIdx.x * 128;

    const int sr = lane >> 2;
    const int sk = (lane & 3) * 8;
    const u16* Ag0 = A  + (size_t)(m0 + 32 * w      + sr) * K + sk;
    const u16* Ag1 = A  + (size_t)(m0 + 32 * w + 16 + sr) * K + sk;
    const u16* Bg0 = Bt + (size_t)(n0 + 32 * w      + sr) * K + sk;
    const u16* Bg1 = Bt + (size_t)(n0 + 32 * w + 16 + sr) * K + sk;
    u16* Al0 = &As[(32 * w)      * 32];
    u16* Al1 = &As[(32 * w + 16) * 32];
    u16* Bl0 = &Bs[(32 * w)      * 32];
    u16* Bl1 = &Bs[(32 * w + 16) * 32];

    v4f acc[4][4];
#pragma unroll
    for (int r = 0; r < 4; ++r)
#pragma unroll
        for (int c = 0; c < 4; ++c) acc[r][c] = (v4f){0.f, 0.f, 0.f, 0.f};

    const int mrow = (w >> 1) * 64;
    const int ncol = (w & 1) * 64;

    for (int k0 = 0; k0 < K; k0 += 32) {
        __syncthreads();
        gl2lds16(Ag0 + k0, Al0);
        gl2lds16(Ag1 + k0, Al1);
        gl2lds16(Bg0 + k0, Bl0);
        gl2lds16(Bg1 + k0, Bl1);
        __syncthreads();

        v8bf af[4], bfr[4];
#pragma unroll
        for (int r = 0; r < 4; ++r)
            af[r] = *(const v8bf*)(&As[(mrow + r * 16 + l16) * 32 + quad * 8]);
#pragma unroll
        for (int c = 0; c < 4; ++c)
            bfr[c] = *(const v8bf*)(&Bs[(ncol + c * 16 + l16) * 32 + quad * 8]);
#pragma unroll
        for (int r = 0; r < 4; ++r)
#pragma unroll
            for (int c = 0; c < 4; ++c)
                acc[r][c] = __builtin_amdgcn_mfma_f32_16x16x32_bf16(
                    af[r], bfr[c], acc[r][c], 0, 0, 0);
    }

#pragma unroll
    for (int r = 0; r < 4; ++r) {
#pragma unroll
        for (int c = 0; c < 4; ++c) {
            const int col = n0 + ncol + c * 16 + l16;
            const float bv = bias[col];
#pragma unroll
            for (int reg = 0; reg < 4; ++reg) {
                const int row = m0 + mrow + r * 16 + quad * 4 + reg;
                const float val = acc[r][c][reg] + bv;
                if (MODE == 0) {
                    Cout[(size_t)row * N + col] = val;
                } else {
                    const int which = col >> 10;
                    const int rem   = col & 1023;
                    const int h     = rem >> 6;
                    const int d     = rem & 63;
                    const int b     = row >> 11;
                    const int n     = row & 2047;
                    u16* dst = (which == 0) ? qOut : (which == 1) ? kOut : vOut;
                    dst[(((size_t)(b * kH + h)) * kN + n) * kD + d] = f2bf(val);
                }
            }
        }
    }
}

// ------------------------------------------------- MFMA attention (bf16)
// Block = 64 q-rows of one (b,h); 4 waves. TK=64 keys/tile -> 24 KB LDS
// -> 6 blocks/CU. Prefetch for tile t+1 issues AFTER sync2 so loads fly
// across the compute phase (barrier drains them exactly at next sync1).
// All LDS staging lane-maps chosen so XOR swizzle varies per lane ->
// 2-way-max bank aliasing (free).
__global__ __launch_bounds__(256, 6) void attn_mfma_kernel(
    const u16* __restrict__ q, const u16* __restrict__ k,
    const u16* __restrict__ v, const u32* __restrict__ mbits,
    u16* __restrict__ out)   // bf16 ao [B,N,C]
{
    __shared__ u16 Ks[64 * 64];   // 8 KB [key][d],  blk ^= key&7
    __shared__ u16 Vt[64 * 64];   // 8 KB [d][key],  blk ^= d&7
    __shared__ u16 Ps[64 * 64];   // 8 KB [q][key],  blk ^= l16&7

    const int t    = threadIdx.x;
    const int w    = t >> 6;
    const int lane = t & 63;
    const int quad = lane >> 4;
    const int l16  = lane & 15;

    const int bh    = blockIdx.x >> 5;
    const int tile0 = (blockIdx.x & 31) * 64;
    const int b     = bh >> 4;
    const int h     = bh & 15;

    const u16* qb = q + (size_t)bh * kN * kD;
    const u16* kb = k + (size_t)bh * kN * kD;
    const u16* vb = v + (size_t)bh * kN * kD;

    // Q B-fragments: lane holds Q[q = w*16+l16][d = quad*8 + j]
    const int qrow = tile0 + w * 16 + l16;
    const v8bf qf0 = *(const v8bf*)(qb + (size_t)qrow * kD + quad * 8);
    const v8bf qf1 = *(const v8bf*)(qb + (size_t)qrow * kD + 32 + quad * 8);

    const u32* mrowb = mbits + ((size_t)b * kN + qrow) * 64;

    // staging geometry: K: lane-per-row; V: key-pair fast, dim slow
    const int skr = t & 63;            // K row 0..63
    const int skb = (t >> 6) * 2;      // K block base (8-elem blocks)
    const u16* kgp = kb + (size_t)skr * kD + skb * 8;
    const int svk = (t & 31) * 2;      // V keys svk, svk+1
    const int svd = (t >> 5) * 8;      // V dims svd..svd+7
    const u16* vgp = vb + (size_t)svk * kD + svd;

    u16* kdst0 = &Ks[skr * 64 + (((skb)     ^ (skr & 7)) * 8)];
    u16* kdst1 = &Ks[skr * 64 + (((skb + 1) ^ (skr & 7)) * 8)];

    u16x8 kpre0, kpre1, vpre0, vpre1;
    u32 mp0, mp1;
    auto prefetch = [&](int k0) {
        const u16* kp = kgp + (size_t)k0 * kD;
        kpre0 = *(const u16x8*)(kp);
        kpre1 = *(const u16x8*)(kp + 8);
        const u16* vp = vgp + (size_t)k0 * kD;
        vpre0 = *(const u16x8*)(vp);
        vpre1 = *(const u16x8*)(vp + kD);
        const uint2 mm = *(const uint2*)(mrowb + (k0 >> 5));
        mp0 = mm.x; mp1 = mm.y;
    };

    v4f oacc[4];
#pragma unroll
    for (int i = 0; i < 4; ++i) oacc[i] = (v4f){0.f, 0.f, 0.f, 0.f};
    float rs = 0.f;

    prefetch(0);

    for (int kt = 0; kt < kN / 64; ++kt) {
        __syncthreads();   // prev tile's LDS reads done (also drains prefetch)

        // ---- K [key][d] swizzled
        *(u16x8*)kdst0 = kpre0;
        *(u16x8*)kdst1 = kpre1;
        // ---- V transposed [d][key] swizzled; d&7=j const but svk>>3 varies
        //      per lane -> 2-way banks max
#pragma unroll
        for (int j = 0; j < 8; ++j) {
            u16x2 p; p.x = vpre0[j]; p.y = vpre1[j];
            *(u16x2*)(&Vt[(svd + j) * 64 + (((svk >> 3) ^ j) * 8) + (svk & 7)]) = p;
        }
        const u32 mc0 = mp0, mc1 = mp1;
        __syncthreads();   // staged tile visible (nothing in vmem queue here)

        if (kt + 1 < kN / 64) prefetch((kt + 1) * 64);   // overlaps compute

        // ---- S^T: D[key = nb*16 + quad*4+reg][q = l16]
#pragma unroll
        for (int nb = 0; nb < 4; ++nb) {
            const int krow = nb * 16 + l16;
            const v8bf kf0 = *(const v8bf*)(&Ks[krow * 64 + (((quad)     ^ (krow & 7)) * 8)]);
            const v8bf kf1 = *(const v8bf*)(&Ks[krow * 64 + (((quad + 4) ^ (krow & 7)) * 8)]);
            v4f s = (v4f){0.f, 0.f, 0.f, 0.f};
            s = __builtin_amdgcn_mfma_f32_16x16x32_bf16(kf0, qf0, s, 0, 0, 0);
            s = __builtin_amdgcn_mfma_f32_16x16x32_bf16(kf1, qf1, s, 0, 0, 0);

            const u32 m4 = ((nb < 2 ? mc0 : mc1) >> ((nb & 1) * 16 + quad * 4)) & 0xFu;
            const float e0 = (m4 & 1u) ? 0.f : fexp2(s[0] * kScaleLog2e);
            const float e1 = (m4 & 2u) ? 0.f : fexp2(s[1] * kScaleLog2e);
            const float e2 = (m4 & 4u) ? 0.f : fexp2(s[2] * kScaleLog2e);
            const float e3 = (m4 & 8u) ? 0.f : fexp2(s[3] * kScaleLog2e);
            rs += (e0 + e1) + (e2 + e3);

            union { u32 wds[2]; u16x4 v4; } pk;
            pk.wds[0] = f2bf_pk(e0, e1);
            pk.wds[1] = f2bf_pk(e2, e3);
            *(u16x4*)(&Ps[(w * 16 + l16) * 64 +
                          (((nb * 2 + (quad >> 1)) ^ (l16 & 7)) * 8) + (quad & 1) * 4]) = pk.v4;
        }
        // no barrier: Ps rows w*16..+15 are wave-private

        // ---- PV: O[q][d] += P(16x64) @ V(64x64)
#pragma unroll
        for (int ks = 0; ks < 2; ++ks) {
            const v8bf pa = *(const v8bf*)(&Ps[(w * 16 + l16) * 64 +
                                               (((ks * 4 + quad) ^ (l16 & 7)) * 8)]);
#pragma unroll
            for (int db = 0; db < 4; ++db) {
                const int d = db * 16 + l16;
                const v8bf vf = *(const v8bf*)(&Vt[d * 64 + (((ks * 4 + quad) ^ (d & 7)) * 8)]);
                oacc[db] = __builtin_amdgcn_mfma_f32_16x16x32_bf16(pa, vf, oacc[db], 0, 0, 0);
            }
        }
    }

    // ---- rowsum: reduce across quads, redistribute per output row
    rs += __shfl_xor(rs, 16);
    rs += __shfl_xor(rs, 32);
    const float inv = 1.f / rs;
    float rq[4];
#pragma unroll
    for (int reg = 0; reg < 4; ++reg)
        rq[reg] = __shfl(inv, quad * 4 + reg);

#pragma unroll
    for (int db = 0; db < 4; ++db) {
#pragma unroll
        for (int reg = 0; reg < 4; ++reg) {
            const int row = tile0 + w * 16 + quad * 4 + reg;
            const int col = h * 64 + db * 16 + l16;
            out[((size_t)(b * kN + row)) * kC + col] = f2bf(oacc[db][reg] * rq[reg]);
        }
    }
}

// ------------------------------------------------------------------ launch
extern "C" void kernel_launch(void* const* d_in, const int* in_sizes, int n_in,
                              void* d_out, int out_size, void* d_ws, size_t ws_size,
                              hipStream_t stream)
{
    const float* x     = (const float*)d_in[0];
    const int*   mask  = (const int*)d_in[1];
    const float* Wqkv  = (const float*)d_in[2];
    const float* bqkv  = (const float*)d_in[3];
    const float* Wproj = (const float*)d_in[4];
    const float* bproj = (const float*)d_in[5];
    float* out = (float*)d_out;

    const size_t nx = (size_t)kB * kN * kC;
    const size_t qkv_elems = (size_t)kB * kH * kN * kD;
    u16* xb     = (u16*)d_ws;
    u16* qbuf   = xb + nx;
    u16* kbuf   = qbuf + qkv_elems;
    u16* vbuf   = kbuf + qkv_elems;
    u16* aob    = vbuf + qkv_elems;
    u16* Wqkvt  = aob + nx;
    u16* Wprojt = Wqkvt + (size_t)3 * kC * kC;
    u32* mbits  = (u32*)(Wprojt + (size_t)kC * kC);   // 2 MB bitmask

    maskpack_kernel<<<dim3(kB * kN * 32 / 4), dim3(256), 0, stream>>>(mask, mbits);
    cast_bf16_kernel<<<dim3(nx / 1024), dim3(256), 0, stream>>>(x, xb);
    tpose_cast_kernel<<<dim3(3 * kC / 64, kC / 64), dim3(256), 0, stream>>>(
        Wqkv, Wqkvt, kC, 3 * kC);
    tpose_cast_kernel<<<dim3(kC / 64, kC / 64), dim3(256), 0, stream>>>(
        Wproj, Wprojt, kC, kC);

    gemm_mfma_kernel<1><<<dim3(3 * kC / 128, kB * kN / 128), dim3(256), 0, stream>>>(
        xb, Wqkvt, bqkv, nullptr, qbuf, kbuf, vbuf, kB * kN, 3 * kC, kC);

    attn_mfma_kernel<<<dim3(kB * kH * (kN / 64)), dim3(256), 0, stream>>>(
        qbuf, kbuf, vbuf, mbits, aob);

    gemm_mfma_kernel<0><<<dim3(kC / 128, kB * kN / 128), dim3(256), 0, stream>>>(
        aob, Wprojt, bproj, out, nullptr, nullptr, nullptr, kB * kN, kC, kC);
}